// Round 14
// baseline (65.320 us; speedup 1.0000x reference)
//
#include <hip/hip_runtime.h>

// ---------------- problem constants ----------------
constexpr int B = 8, H = 100, W = 100, A = 9, G = 50, K = 18;
constexpr int NPROP = B * H * W * A;   // 720000
constexpr int NPOS  = B * H * W;       // 80000
constexpr float THR = 0.7f;

#define JAX_PARTITIONABLE 1

#define TPB 576                  // 9 waves; 1152 proposals = 128 positions per block
#define NB_P 625                 // producer blocks
#define GRID (NB_P + 1)          // + spin consumer block (R3/R4-proven sync)
#define NBIN 2560                // bin = key>>43 = delta>>11; delta<=0x4CCCCC -> bin<=2457
#define BINCAP 512               // keys per bucket (typ. max ~tens; spill handles rest)
#define SPILL_CAP 16384
#define BLK_CAND 1024            // LDS gather buffer cap

// ---------------- device state (zero at load; consumer resets each launch) ----
__device__ unsigned int g_bincnt[NBIN];              // true per-bin counts (atomic)
__device__ int g_spillCount;
__device__ int g_done;
__device__ unsigned long long g_bins[(size_t)NBIN * BINCAP];  // 10 MB buckets
__device__ unsigned long long g_spill[SPILL_CAP];
__device__ unsigned long long g_negtop[NB_P * 10];   // per-block neg top-10 (0-padded)

// ---------------- threefry2x32 (JAX-exact) ----------------
__device__ __forceinline__ unsigned int rotl32(unsigned int x, int r) {
    return (x << r) | (x >> (32 - r));
}
__device__ __forceinline__ void tfr(unsigned int& x0, unsigned int& x1, int r) {
    x0 += x1; x1 = rotl32(x1, r); x1 ^= x0;
}
__device__ void threefry2x32(unsigned int k0, unsigned int k1,
                             unsigned int c0, unsigned int c1,
                             unsigned int& o0, unsigned int& o1) {
    unsigned int ks2 = k0 ^ k1 ^ 0x1BD11BDAu;
    unsigned int x0 = c0 + k0, x1 = c1 + k1;
    tfr(x0,x1,13); tfr(x0,x1,15); tfr(x0,x1,26); tfr(x0,x1, 6);
    x0 += k1;  x1 += ks2 + 1u;
    tfr(x0,x1,17); tfr(x0,x1,29); tfr(x0,x1,16); tfr(x0,x1,24);
    x0 += ks2; x1 += k0 + 2u;
    tfr(x0,x1,13); tfr(x0,x1,15); tfr(x0,x1,26); tfr(x0,x1, 6);
    x0 += k0;  x1 += k1 + 3u;
    tfr(x0,x1,17); tfr(x0,x1,29); tfr(x0,x1,16); tfr(x0,x1,24);
    x0 += k1;  x1 += ks2 + 4u;
    tfr(x0,x1,13); tfr(x0,x1,15); tfr(x0,x1,26); tfr(x0,x1, 6);
    x0 += ks2; x1 += k0 + 5u;
    o0 = x0; o1 = x1;
}

__device__ void derive_keys(unsigned int& kp0, unsigned int& kp1,
                            unsigned int& kn0, unsigned int& kn1) {
#if JAX_PARTITIONABLE
    threefry2x32(0u, 42u, 0u, 0u, kp0, kp1);
    threefry2x32(0u, 42u, 0u, 1u, kn0, kn1);
#else
    unsigned int a0, b0, a1, b1;
    threefry2x32(0u, 42u, 0u, 2u, a0, b0);
    threefry2x32(0u, 42u, 1u, 3u, a1, b1);
    kp0 = a0; kp1 = a1; kn0 = b0; kn1 = b1;
#endif
}

__device__ float jax_uniform(unsigned int k0, unsigned int k1, unsigned int i, unsigned int n) {
    unsigned int bits;
#if JAX_PARTITIONABLE
    unsigned int o0, o1;
    threefry2x32(k0, k1, 0u, i, o0, o1);
    bits = o0 ^ o1;
#else
    unsigned int half = n >> 1;
    unsigned int o0, o1;
    if (i < half) { threefry2x32(k0, k1, i, i + half, o0, o1); bits = o0; }
    else          { threefry2x32(k0, k1, i - half, i, o0, o1); bits = o1; }
#endif
    unsigned int fb = (bits >> 9) | 0x3F800000u;
    return __uint_as_float(fb) - 1.0f;
}

__device__ __forceinline__ void emit_candidate(float iou, unsigned int idx) {
    unsigned int delta = __float_as_uint(iou) - 0x3F333334u;   // <= 0x4CCCCC
    unsigned long long key = ((unsigned long long)delta << 32)
                           | (unsigned long long)(~idx);
    unsigned int bin = (unsigned int)(key >> 43);              // <= 2457 < NBIN
    unsigned int slot = atomicAdd(&g_bincnt[bin], 1u);
    if (slot < BINCAP) g_bins[(size_t)bin * BINCAP + slot] = key;
    else { int gs = atomicAdd(&g_spillCount, 1);
           if (gs < SPILL_CAP) g_spill[gs] = key; }
}

// ======================= single fused kernel =======================
__global__ __launch_bounds__(TPB) void fused_kernel(
        const float* __restrict__ proposals, const float* __restrict__ cls_prob,
        const float* __restrict__ anchor_prob, const float* __restrict__ gtp,
        const int* __restrict__ gtc, float* __restrict__ out) {
    // producer-phase LDS
    __shared__ float  s41[G];
    __shared__ unsigned int sflag[128];
    __shared__ unsigned long long snk[128];
    __shared__ unsigned long long wk[10];
    // consumer-phase LDS
    __shared__ unsigned int hist[NBIN];      // 10 KB
    __shared__ int sfx[256];
    __shared__ unsigned int rhist[2048];
    __shared__ unsigned long long cbuf[BLK_CAND];
    __shared__ unsigned long long lst[100];
    __shared__ unsigned long long skeys[128];
    __shared__ unsigned long long swin[10];
    __shared__ unsigned long long wred[9];
    __shared__ int selIdx[10];
    __shared__ int s_g[10], s_a[10], s_pos[10], s_bb[10], s_hh[10], s_ww[10], s_npos[10];
    __shared__ int sh_d, sh_before, sh_C, sh_d2, sh_cnt, sh_ovf;

    const int t = threadIdx.x;
    const int bid = blockIdx.x;
    const float4* gtp4 = reinterpret_cast<const float4*>(gtp);   // uniform -> scalar loads

    if (bid < NB_P) {
        // ================= producer (R7/R12-proven math; bucket emit) =================
        if (t < G) {
            float4 gb = gtp4[t];
            s41[t] = __fmul_rn(0.41f, __fmul_rn(__fsub_rn(gb.z, gb.x), __fsub_rn(gb.w, gb.y)));
        }
        if (t < 128) sflag[t] = 0u;
        __syncthreads();

        int p0 = bid * 1152 + t;
        float4 x0 = reinterpret_cast<const float4*>(proposals)[p0];
        float4 x1 = reinterpret_cast<const float4*>(proposals)[p0 + 576];
        float ap0 = __fmul_rn(__fsub_rn(x0.z, x0.x), __fsub_rn(x0.w, x0.y));
        float ap1 = __fmul_rn(__fsub_rn(x1.z, x1.x), __fsub_rn(x1.w, x1.y));
        float a41_0 = __fmul_rn(0.41f, ap0);
        float a41_1 = __fmul_rn(0.41f, ap1);
        int li = t / 9, a = t - li * 9;
        int base0 = (bid * 128 + li) * (G * A) + a;
        int base1 = (bid * 128 + 64 + li) * (G * A) + a;
        unsigned f0 = 0u, f1 = 0u;

        for (int g = 0; g < G; ++g) {
            float4 gb = gtp4[g];
            float sg41 = s41[g];
            {
                float dx = __fsub_rn(fminf(x0.z, gb.z), fmaxf(x0.x, gb.x));
                float dy = __fsub_rn(fminf(x0.w, gb.w), fmaxf(x0.y, gb.y));
                float inter = __fmul_rn(fmaxf(dx, 0.0f), fmaxf(dy, 0.0f));
                // screen: fail => iou <= ~0.695 < 0.7 (margin >> ulp). exact path below.
                if (inter > __fadd_rn(a41_0, sg41)) {
                    float ag = __fmul_rn(__fsub_rn(gb.z, gb.x), __fsub_rn(gb.w, gb.y));
                    float den = __fadd_rn(__fsub_rn(__fadd_rn(ap0, ag), inter), 1e-8f);
                    float iou = __fdiv_rn(inter, den);
                    if (iou >= THR) f0 = 1u;
                    if (iou > THR) emit_candidate(iou, (unsigned int)(base0 + g * A));
                }
            }
            {
                float dx = __fsub_rn(fminf(x1.z, gb.z), fmaxf(x1.x, gb.x));
                float dy = __fsub_rn(fminf(x1.w, gb.w), fmaxf(x1.y, gb.y));
                float inter = __fmul_rn(fmaxf(dx, 0.0f), fmaxf(dy, 0.0f));
                if (inter > __fadd_rn(a41_1, sg41)) {
                    float ag = __fmul_rn(__fsub_rn(gb.z, gb.x), __fsub_rn(gb.w, gb.y));
                    float den = __fadd_rn(__fsub_rn(__fadd_rn(ap1, ag), inter), 1e-8f);
                    float iou = __fdiv_rn(inter, den);
                    if (iou >= THR) f1 = 1u;
                    if (iou > THR) emit_candidate(iou, (unsigned int)(base1 + g * A));
                }
            }
        }
        if (f0) atomicOr(&sflag[li], 1u);
        if (f1) atomicOr(&sflag[li + 64], 1u);
        if (t < 10) wk[t] = 0ull;
        __syncthreads();

        // negative keys for this block's 128 positions
        if (t < 128) {
            unsigned int kp0, kp1, kn0, kn1;
            derive_keys(kp0, kp1, kn0, kn1);
            unsigned long long key = 0ull;
            if (sflag[t] == 0u) {
                unsigned int pos = (unsigned)(bid * 128 + t);
                float u = jax_uniform(kn0, kn1, pos, (unsigned)NPOS);
                key = ((unsigned long long)__float_as_uint(u) << 32)
                    | (unsigned long long)(~pos);
            }
            snk[t] = key;
        }
        __syncthreads();
        if (t < 128) {
            unsigned long long k2 = snk[t];
            if (k2 != 0ull) {
                int r = 0;
                for (int j = 0; j < 128; ++j) r += (snk[j] > k2) ? 1 : 0;
                if (r < 10) wk[r] = k2;       // ranks unique (keys unique)
            }
        }
        __syncthreads();
        if (t < 10) g_negtop[bid * 10 + t] = wk[t];
        __syncthreads();
        if (t == 0)   // R3/R4-proven release
            __hip_atomic_fetch_add(&g_done, 1, __ATOMIC_RELEASE, __HIP_MEMORY_SCOPE_AGENT);
        return;
    }

    // ================= consumer: spin (R3/R4-proven), then select =================
    if (t == 0) {
        while (__hip_atomic_load(&g_done, __ATOMIC_ACQUIRE, __HIP_MEMORY_SCOPE_AGENT) < NB_P)
            __builtin_amdgcn_s_sleep(8);
    }
    __syncthreads();

    // ---- load per-bin counts; chunked suffix scan (256 chunks x 10 bins, R12-proven) ----
    for (int i = t; i < NBIN; i += TPB) hist[i] = g_bincnt[i];
    if (t == 0) { sh_d = NBIN - 1; sh_before = 0; sh_ovf = 0; sh_cnt = 0; }
    __syncthreads();
    if (t < 256) {
        int ps = 0;
        for (int q = 0; q < 10; ++q) ps += (int)hist[t * 10 + q];
        sfx[t] = ps;
    }
    __syncthreads();
    if (t < 64) {
        int lane = t;
        int c0 = sfx[4*lane+0], c1 = sfx[4*lane+1], c2 = sfx[4*lane+2], c3 = sfx[4*lane+3];
        int tot = c0 + c1 + c2 + c3;
        int acc = tot;
        for (int s = 1; s < 64; s <<= 1) {
            int u = __shfl_down(acc, s);
            if (lane + s < 64) acc += u;
        }
        int C = __shfl(acc, 0);           // suffix from chunk 0 = total candidates
        if (lane == 0) sh_C = C;
        int need = C < 100 ? C : 100;
        int aboveG = acc - tot;           // count in chunks > 4*lane+3
        int CS3 = aboveG;
        int CS2 = CS3 + c3;
        int CS1 = CS2 + c2;
        int CS0 = CS1 + c1;
        int CSv[4] = {CS0, CS1, CS2, CS3};
        int cv[4]  = {c0, c1, c2, c3};
#pragma unroll
        for (int j = 0; j < 4; ++j) {
            if (CSv[j] < need && CSv[j] + cv[j] >= need) {
                int cum = CSv[j];
                int cbin = 4*lane + j;
                for (int b = cbin*10 + 9; b >= cbin*10; --b) {
                    int h = (int)hist[b];
                    if (cum + h >= need) { sh_d = b; sh_before = cum; break; }
                    cum += h;
                }
            }
        }
    }
    __syncthreads();
    int C = sh_C;
    int needTotal = C < 100 ? C : 100;
    int d = sh_d, sb = sh_before;
    int tie = (int)hist[d];
    unsigned long long lo = ((unsigned long long)(unsigned)d) << 43;
    int spillN = g_spillCount; if (spillN > SPILL_CAP) spillN = SPILL_CAP;

    // any overflowed bin among the needed range?
    for (int b = d + t; b < NBIN; b += TPB)
        if (hist[b] > BINCAP) sh_ovf = 1;
    __syncthreads();

    if (sb + tie > BLK_CAND) {
        // ---- cold refine: sub-histogram of bin d on full remaining delta bits ----
        for (int i = t; i < 2048; i += TPB) rhist[i] = 0u;
        __syncthreads();
        int stored_d = tie < BINCAP ? tie : BINCAP;
        for (int i = t; i < stored_d; i += TPB) {
            unsigned long long k2 = g_bins[(size_t)d * BINCAP + i];
            atomicAdd(&rhist[(unsigned)(k2 >> 32) & 0x7FFu], 1u);
        }
        if (tie > BINCAP) {
            for (int i = t; i < spillN; i += TPB) {
                unsigned long long k2 = g_spill[i];
                if ((unsigned)(k2 >> 43) == (unsigned)d)
                    atomicAdd(&rhist[(unsigned)(k2 >> 32) & 0x7FFu], 1u);
            }
        }
        __syncthreads();
        if (t == 0) {
            int need = needTotal, cum = sb;
            sh_d2 = 0;
            for (int b2 = 2047; b2 >= 0; --b2) {
                int h2 = (int)rhist[b2];
                if (cum + h2 >= need) { sh_d2 = b2; break; }
                cum += h2;
            }
        }
        __syncthreads();
        lo |= ((unsigned long long)(unsigned)sh_d2) << 32;
    }

    // ---- gather keys >= lo from buckets d..NBIN (parallel over bins) + spill ----
    for (int b = d + t; b < NBIN; b += TPB) {
        int cnt_b = (int)hist[b]; if (cnt_b > BINCAP) cnt_b = BINCAP;
        for (int i = 0; i < cnt_b; ++i) {
            unsigned long long k2 = g_bins[(size_t)b * BINCAP + i];
            if (k2 >= lo) {
                int s2 = atomicAdd(&sh_cnt, 1);
                if (s2 < BLK_CAND) cbuf[s2] = k2;
            }
        }
    }
    if (sh_ovf) {
        for (int i = t; i < spillN; i += TPB) {
            unsigned long long k2 = g_spill[i];
            if (k2 >= lo) {
                int s2 = atomicAdd(&sh_cnt, 1);
                if (s2 < BLK_CAND) cbuf[s2] = k2;
            }
        }
    }
    __syncthreads();
    int M = sh_cnt < BLK_CAND ? sh_cnt : BLK_CAND;

    // sorted top-needTotal via parallel rank-count (keys unique)
    for (int i = t; i < M; i += TPB) {
        unsigned long long ki = cbuf[i];
        int r = 0;
        for (int j = 0; j < M; ++j) r += (cbuf[j] > ki) ? 1 : 0;
        if (r < needTotal) lst[r] = ki;
    }
    __syncthreads();

    unsigned int kp0, kp1, kn0, kn1;
    derive_keys(kp0, kp1, kn0, kn1);
    if (t < needTotal) {
        float u = jax_uniform(kp0, kp1, (unsigned)t, 100u);
        skeys[t] = ((unsigned long long)__float_as_uint(u) << 32)
                 | (unsigned long long)(~(unsigned)t);
    }
    __syncthreads();
    if (t < needTotal) {
        unsigned long long s = skeys[t];
        int r = 0;
        for (int j = 0; j < needTotal; ++j) r += (skeys[j] > s) ? 1 : 0;
        if (r < 10) selIdx[r] = t;
    }
    __syncthreads();

    if (t < 10) {   // decode positives into LDS staging
        unsigned long long key = lst[selIdx[t]];
        unsigned int fidx = ~(unsigned int)(key & 0xFFFFFFFFull);
        int aa = fidx % A; unsigned int rest = fidx / A;
        int gg = rest % G; rest /= G;
        int ww = rest % W; rest /= W;
        int hh = rest % H; int bb = rest / H;
        s_a[t] = aa; s_g[t] = gg; s_ww[t] = ww; s_hh[t] = hh; s_bb[t] = bb;
        s_pos[t] = (bb * H + hh) * W + ww;
    }

    // -------- negatives merge: 6250 keys -> global top-10 (R10-proven code) --------
    unsigned long long top[10];
#pragma unroll
    for (int j = 0; j < 10; ++j) top[j] = 0ull;
    for (int i = t; i < NB_P * 10; i += TPB) {
        unsigned long long key = g_negtop[i];
#pragma unroll
        for (int j = 0; j < 10; ++j) {
            if (key > top[j]) { unsigned long long tmp = top[j]; top[j] = key; key = tmp; }
        }
    }
    int lane = t & 63, wid = t >> 6;     // 9 waves
    for (int r = 0; r < 10; ++r) {
        unsigned long long w = top[0];
        for (int s = 1; s < 64; s <<= 1) {
            unsigned long long o = __shfl_xor(w, s);
            if (o > w) w = o;
        }
        if (lane == 0) wred[wid] = w;
        __syncthreads();
        unsigned long long m = wred[0];
#pragma unroll
        for (int i = 1; i < 9; ++i) { unsigned long long x = wred[i]; if (x > m) m = x; }
        if (t == 0) swin[r] = m;
        if (top[0] == m) {
#pragma unroll
            for (int j = 0; j < 9; ++j) top[j] = top[j + 1];
            top[9] = 0ull;
        }
        __syncthreads();
    }
    if (t < 10) s_npos[t] = (int)(~(unsigned int)(swin[t] & 0xFFFFFFFFull));
    __syncthreads();

    // -------- flat cooperative gather: 720 outputs, 1 load each --------
    for (int e = t; e < 720; e += TPB) {
        float v;
        if (e < 50)       { int i = e / 5, f = e - 5 * i;
                            v = (float)((f==0)?s_bb[i]:(f==1)?s_hh[i]:(f==2)?s_ww[i]:(f==3)?s_g[i]:s_a[i]); }
        else if (e < 90)  { int u = e - 50, i = u >> 2, q = u & 3;
                            v = proposals[(size_t)(s_pos[i] * A + s_a[i]) * 4 + q]; }
        else if (e < 270) { int u = e - 90, i = u / 18, q = u - 18 * i;
                            v = cls_prob[(size_t)s_pos[i] * K + q]; }
        else if (e < 310) { int u = e - 270, i = u >> 2, q = u & 3;
                            v = gtp[s_g[i] * 4 + q]; }
        else if (e < 320) { v = (float)gtc[s_g[e - 310]]; }
        else if (e < 330) { v = (float)s_a[e - 320]; }
        else if (e < 510) { int u = e - 330, i = u / 18, q = u - 18 * i;
                            v = anchor_prob[(size_t)s_pos[i] * K + q]; }
        else if (e < 540) { int u = e - 510, i = u / 3, f = u - 3 * i; int p = s_npos[i];
                            v = (float)((f==0) ? (p / (H * W)) : (f==1) ? ((p / W) % H) : (p % W)); }
        else              { int u = e - 540, i = u / 18, q = u - 18 * i;
                            v = cls_prob[(size_t)s_npos[i] * K + q]; }
        out[e] = v;
    }

    // -------- reset device state for next replay (R3-proven pattern) --------
    __syncthreads();
    for (int i = t; i < NBIN; i += TPB) g_bincnt[i] = 0u;
    if (t == 0) {
        g_spillCount = 0;
        __hip_atomic_store(&g_done, 0, __ATOMIC_RELEASE, __HIP_MEMORY_SCOPE_AGENT);
    }
}

// ---------------- launcher ----------------
extern "C" void kernel_launch(void* const* d_in, const int* in_sizes, int n_in,
                              void* d_out, int out_size, void* d_ws, size_t ws_size,
                              hipStream_t stream) {
    const float* proposals   = (const float*)d_in[0];
    const float* cls_prob    = (const float*)d_in[1];
    const float* anchor_prob = (const float*)d_in[2];
    const float* gtp         = (const float*)d_in[3];
    const int*   gtc         = (const int*)d_in[4];
    float* out = (float*)d_out;

    fused_kernel<<<GRID, TPB, 0, stream>>>(proposals, cls_prob, anchor_prob, gtp, gtc, out);
}

// Round 15
// 41.640 us; speedup vs baseline: 1.5687x; 1.5687x over previous
//
#include <hip/hip_runtime.h>

// ---------------- problem constants ----------------
constexpr int B = 8, H = 100, W = 100, A = 9, G = 50, K = 18;
constexpr int NPROP = B * H * W * A;   // 720000
constexpr int NPOS  = B * H * W;       // 80000
constexpr float THR = 0.7f;

#define JAX_PARTITIONABLE 1

#define TPB 576                  // 9 waves; 1152 proposals = 128 positions per block
#define NB_P 625                 // producer blocks
#define TPC 512                  // consumer threads (8 waves) x 2 blocks
#define NBIN 2560                // bin = key>>43 = delta>>11; delta<=0x4CCCCC -> bin<=2457
#define BINCAP 512               // keys per bucket
#define SPILL_CAP 16384
#define BLK_CAND 1024            // LDS gather buffer cap

// ---------------- device state (zero at load; consumer resets each launch) ----
__device__ unsigned int g_bincnt[NBIN];              // true per-bin counts (atomic)
__device__ int g_spillCount;
__device__ unsigned long long g_bins[(size_t)NBIN * BINCAP];
__device__ unsigned long long g_spill[SPILL_CAP];
__device__ unsigned long long g_negtop[NB_P * 10];   // per-block neg top-10 (0-padded)

// ---------------- threefry2x32 (JAX-exact) ----------------
__device__ __forceinline__ unsigned int rotl32(unsigned int x, int r) {
    return (x << r) | (x >> (32 - r));
}
__device__ __forceinline__ void tfr(unsigned int& x0, unsigned int& x1, int r) {
    x0 += x1; x1 = rotl32(x1, r); x1 ^= x0;
}
__device__ void threefry2x32(unsigned int k0, unsigned int k1,
                             unsigned int c0, unsigned int c1,
                             unsigned int& o0, unsigned int& o1) {
    unsigned int ks2 = k0 ^ k1 ^ 0x1BD11BDAu;
    unsigned int x0 = c0 + k0, x1 = c1 + k1;
    tfr(x0,x1,13); tfr(x0,x1,15); tfr(x0,x1,26); tfr(x0,x1, 6);
    x0 += k1;  x1 += ks2 + 1u;
    tfr(x0,x1,17); tfr(x0,x1,29); tfr(x0,x1,16); tfr(x0,x1,24);
    x0 += ks2; x1 += k0 + 2u;
    tfr(x0,x1,13); tfr(x0,x1,15); tfr(x0,x1,26); tfr(x0,x1, 6);
    x0 += k0;  x1 += k1 + 3u;
    tfr(x0,x1,17); tfr(x0,x1,29); tfr(x0,x1,16); tfr(x0,x1,24);
    x0 += k1;  x1 += ks2 + 4u;
    tfr(x0,x1,13); tfr(x0,x1,15); tfr(x0,x1,26); tfr(x0,x1, 6);
    x0 += ks2; x1 += k0 + 5u;
    o0 = x0; o1 = x1;
}

__device__ void derive_keys(unsigned int& kp0, unsigned int& kp1,
                            unsigned int& kn0, unsigned int& kn1) {
#if JAX_PARTITIONABLE
    threefry2x32(0u, 42u, 0u, 0u, kp0, kp1);
    threefry2x32(0u, 42u, 0u, 1u, kn0, kn1);
#else
    unsigned int a0, b0, a1, b1;
    threefry2x32(0u, 42u, 0u, 2u, a0, b0);
    threefry2x32(0u, 42u, 1u, 3u, a1, b1);
    kp0 = a0; kp1 = a1; kn0 = b0; kn1 = b1;
#endif
}

__device__ float jax_uniform(unsigned int k0, unsigned int k1, unsigned int i, unsigned int n) {
    unsigned int bits;
#if JAX_PARTITIONABLE
    unsigned int o0, o1;
    threefry2x32(k0, k1, 0u, i, o0, o1);
    bits = o0 ^ o1;
#else
    unsigned int half = n >> 1;
    unsigned int o0, o1;
    if (i < half) { threefry2x32(k0, k1, i, i + half, o0, o1); bits = o0; }
    else          { threefry2x32(k0, k1, i - half, i, o0, o1); bits = o1; }
#endif
    unsigned int fb = (bits >> 9) | 0x3F800000u;
    return __uint_as_float(fb) - 1.0f;
}

__device__ __forceinline__ void emit_candidate(float iou, unsigned int idx) {
    unsigned int delta = __float_as_uint(iou) - 0x3F333334u;   // <= 0x4CCCCC
    unsigned long long key = ((unsigned long long)delta << 32)
                           | (unsigned long long)(~idx);
    unsigned int bin = (unsigned int)(key >> 43);              // <= 2457 < NBIN
    unsigned int slot = atomicAdd(&g_bincnt[bin], 1u);
    if (slot < BINCAP) g_bins[(size_t)bin * BINCAP + slot] = key;
    else { int gs = atomicAdd(&g_spillCount, 1);
           if (gs < SPILL_CAP) g_spill[gs] = key; }
}

// ======================= kernel 1: producers =======================
__global__ __launch_bounds__(TPB) void prod_kernel(
        const float* __restrict__ proposals, const float* __restrict__ gtp) {
    __shared__ float  s41[G];           // 0.41 * area_g  (only LDS read in hot loop)
    __shared__ unsigned int sflag[128];
    __shared__ unsigned long long snk[128];
    __shared__ unsigned long long wk[10];

    const int t = threadIdx.x;
    const int bid = blockIdx.x;
    const float4* gtp4 = reinterpret_cast<const float4*>(gtp);   // uniform -> scalar loads

    if (t < G) {
        float4 gb = gtp4[t];
        s41[t] = __fmul_rn(0.41f, __fmul_rn(__fsub_rn(gb.z, gb.x), __fsub_rn(gb.w, gb.y)));
    }
    if (t < 128) sflag[t] = 0u;
    __syncthreads();

    int p0 = bid * 1152 + t;
    float4 x0 = reinterpret_cast<const float4*>(proposals)[p0];
    float4 x1 = reinterpret_cast<const float4*>(proposals)[p0 + 576];
    float ap0 = __fmul_rn(__fsub_rn(x0.z, x0.x), __fsub_rn(x0.w, x0.y));
    float ap1 = __fmul_rn(__fsub_rn(x1.z, x1.x), __fsub_rn(x1.w, x1.y));
    float a41_0 = __fmul_rn(0.41f, ap0);
    float a41_1 = __fmul_rn(0.41f, ap1);
    int li = t / 9, a = t - li * 9;
    int base0 = (bid * 128 + li) * (G * A) + a;
    int base1 = (bid * 128 + 64 + li) * (G * A) + a;
    unsigned f0 = 0u, f1 = 0u;

    for (int g = 0; g < G; ++g) {
        float4 gb = gtp4[g];            // wave-uniform -> scalar loads
        float sg41 = s41[g];
        {
            float dx = __fsub_rn(fminf(x0.z, gb.z), fmaxf(x0.x, gb.x));
            float dy = __fsub_rn(fminf(x0.w, gb.w), fmaxf(x0.y, gb.y));
            float inter = __fmul_rn(fmaxf(dx, 0.0f), fmaxf(dy, 0.0f));
            // screen: fail => iou <= ~0.695 < 0.7 (margin >> ulp). exact path below.
            if (inter > __fadd_rn(a41_0, sg41)) {
                float ag = __fmul_rn(__fsub_rn(gb.z, gb.x), __fsub_rn(gb.w, gb.y));
                float den = __fadd_rn(__fsub_rn(__fadd_rn(ap0, ag), inter), 1e-8f);
                float iou = __fdiv_rn(inter, den);
                if (iou >= THR) f0 = 1u;
                if (iou > THR) emit_candidate(iou, (unsigned int)(base0 + g * A));
            }
        }
        {
            float dx = __fsub_rn(fminf(x1.z, gb.z), fmaxf(x1.x, gb.x));
            float dy = __fsub_rn(fminf(x1.w, gb.w), fmaxf(x1.y, gb.y));
            float inter = __fmul_rn(fmaxf(dx, 0.0f), fmaxf(dy, 0.0f));
            if (inter > __fadd_rn(a41_1, sg41)) {
                float ag = __fmul_rn(__fsub_rn(gb.z, gb.x), __fsub_rn(gb.w, gb.y));
                float den = __fadd_rn(__fsub_rn(__fadd_rn(ap1, ag), inter), 1e-8f);
                float iou = __fdiv_rn(inter, den);
                if (iou >= THR) f1 = 1u;
                if (iou > THR) emit_candidate(iou, (unsigned int)(base1 + g * A));
            }
        }
    }
    if (f0) atomicOr(&sflag[li], 1u);
    if (f1) atomicOr(&sflag[li + 64], 1u);
    if (t < 10) wk[t] = 0ull;
    __syncthreads();

    // negative keys for this block's 128 positions
    if (t < 128) {
        unsigned int kp0, kp1, kn0, kn1;
        derive_keys(kp0, kp1, kn0, kn1);
        unsigned long long key = 0ull;
        if (sflag[t] == 0u) {
            unsigned int pos = (unsigned)(bid * 128 + t);
            float u = jax_uniform(kn0, kn1, pos, (unsigned)NPOS);
            key = ((unsigned long long)__float_as_uint(u) << 32)
                | (unsigned long long)(~pos);
        }
        snk[t] = key;
    }
    __syncthreads();
    if (t < 128) {
        unsigned long long k2 = snk[t];
        if (k2 != 0ull) {
            int r = 0;
            for (int j = 0; j < 128; ++j) r += (snk[j] > k2) ? 1 : 0;
            if (r < 10) wk[r] = k2;       // ranks unique (keys unique)
        }
    }
    __syncthreads();
    if (t < 10) g_negtop[bid * 10 + t] = wk[t];
}

// ============ kernel 2: consumer — block 0 positives, block 1 negatives ============
__global__ __launch_bounds__(TPC) void cons_kernel(
        const float* __restrict__ proposals, const float* __restrict__ cls_prob,
        const float* __restrict__ anchor_prob, const float* __restrict__ gtp,
        const int* __restrict__ gtc, float* __restrict__ out) {
    __shared__ unsigned int hist[NBIN];      // 10 KB
    __shared__ int sfx[256];
    __shared__ unsigned int rhist[2048];
    __shared__ unsigned long long cbuf[BLK_CAND];
    __shared__ unsigned long long lst[100];
    __shared__ unsigned long long skeys[128];
    __shared__ unsigned long long swin[10];
    __shared__ unsigned long long wred[8];
    __shared__ int selIdx[10];
    __shared__ int s_g[10], s_a[10], s_pos[10], s_bb[10], s_hh[10], s_ww[10], s_npos[10];
    __shared__ int sh_d, sh_before, sh_C, sh_d2, sh_cnt, sh_ovf;

    const int t = threadIdx.x;

    if (blockIdx.x == 0) {
        // ---------------- positives (bucket-based, R14-proven logic) ----------------
        for (int i = t; i < NBIN; i += TPC) hist[i] = g_bincnt[i];
        if (t == 0) { sh_d = NBIN - 1; sh_before = 0; sh_ovf = 0; sh_cnt = 0; }
        __syncthreads();
        if (t < 256) {
            int ps = 0;
            for (int q = 0; q < 10; ++q) ps += (int)hist[t * 10 + q];
            sfx[t] = ps;
        }
        __syncthreads();
        if (t < 64) {
            int lane = t;
            int c0 = sfx[4*lane+0], c1 = sfx[4*lane+1], c2 = sfx[4*lane+2], c3 = sfx[4*lane+3];
            int tot = c0 + c1 + c2 + c3;
            int acc = tot;
            for (int s = 1; s < 64; s <<= 1) {
                int u = __shfl_down(acc, s);
                if (lane + s < 64) acc += u;
            }
            int C = __shfl(acc, 0);           // total candidates
            if (lane == 0) sh_C = C;
            int need = C < 100 ? C : 100;
            int aboveG = acc - tot;           // count in chunks > 4*lane+3
            int CS3 = aboveG;
            int CS2 = CS3 + c3;
            int CS1 = CS2 + c2;
            int CS0 = CS1 + c1;
            int CSv[4] = {CS0, CS1, CS2, CS3};
            int cv[4]  = {c0, c1, c2, c3};
#pragma unroll
            for (int j = 0; j < 4; ++j) {
                if (CSv[j] < need && CSv[j] + cv[j] >= need) {
                    int cum = CSv[j];
                    int cbin = 4*lane + j;
                    for (int b = cbin*10 + 9; b >= cbin*10; --b) {
                        int h = (int)hist[b];
                        if (cum + h >= need) { sh_d = b; sh_before = cum; break; }
                        cum += h;
                    }
                }
            }
        }
        __syncthreads();
        int C = sh_C;
        int needTotal = C < 100 ? C : 100;
        int d = sh_d, sb = sh_before;
        int tie = (int)hist[d];
        unsigned long long lo = ((unsigned long long)(unsigned)d) << 43;
        int spillN = g_spillCount; if (spillN > SPILL_CAP) spillN = SPILL_CAP;

        for (int b = d + t; b < NBIN; b += TPC)
            if (hist[b] > BINCAP) sh_ovf = 1;
        __syncthreads();

        if (sb + tie > BLK_CAND) {
            // cold refine: sub-histogram of bin d on remaining delta bits
            for (int i = t; i < 2048; i += TPC) rhist[i] = 0u;
            __syncthreads();
            int stored_d = tie < BINCAP ? tie : BINCAP;
            for (int i = t; i < stored_d; i += TPC) {
                unsigned long long k2 = g_bins[(size_t)d * BINCAP + i];
                atomicAdd(&rhist[(unsigned)(k2 >> 32) & 0x7FFu], 1u);
            }
            if (tie > BINCAP) {
                for (int i = t; i < spillN; i += TPC) {
                    unsigned long long k2 = g_spill[i];
                    if ((unsigned)(k2 >> 43) == (unsigned)d)
                        atomicAdd(&rhist[(unsigned)(k2 >> 32) & 0x7FFu], 1u);
                }
            }
            __syncthreads();
            if (t == 0) {
                int need = needTotal, cum = sb;
                sh_d2 = 0;
                for (int b2 = 2047; b2 >= 0; --b2) {
                    int h2 = (int)rhist[b2];
                    if (cum + h2 >= need) { sh_d2 = b2; break; }
                    cum += h2;
                }
            }
            __syncthreads();
            lo |= ((unsigned long long)(unsigned)sh_d2) << 32;
        }

        // gather keys >= lo from buckets d..NBIN (+ spill if any overflow)
        for (int b = d + t; b < NBIN; b += TPC) {
            int cnt_b = (int)hist[b]; if (cnt_b > BINCAP) cnt_b = BINCAP;
            for (int i = 0; i < cnt_b; ++i) {
                unsigned long long k2 = g_bins[(size_t)b * BINCAP + i];
                if (k2 >= lo) {
                    int s2 = atomicAdd(&sh_cnt, 1);
                    if (s2 < BLK_CAND) cbuf[s2] = k2;
                }
            }
        }
        if (sh_ovf) {
            for (int i = t; i < spillN; i += TPC) {
                unsigned long long k2 = g_spill[i];
                if (k2 >= lo) {
                    int s2 = atomicAdd(&sh_cnt, 1);
                    if (s2 < BLK_CAND) cbuf[s2] = k2;
                }
            }
        }
        __syncthreads();
        int M = sh_cnt < BLK_CAND ? sh_cnt : BLK_CAND;

        // sorted top-needTotal via parallel rank-count (keys unique)
        for (int i = t; i < M; i += TPC) {
            unsigned long long ki = cbuf[i];
            int r = 0;
            for (int j = 0; j < M; ++j) r += (cbuf[j] > ki) ? 1 : 0;
            if (r < needTotal) lst[r] = ki;
        }
        __syncthreads();

        unsigned int kp0, kp1, kn0, kn1;
        derive_keys(kp0, kp1, kn0, kn1);
        if (t < needTotal) {
            float u = jax_uniform(kp0, kp1, (unsigned)t, 100u);
            skeys[t] = ((unsigned long long)__float_as_uint(u) << 32)
                     | (unsigned long long)(~(unsigned)t);
        }
        __syncthreads();
        if (t < needTotal) {
            unsigned long long s = skeys[t];
            int r = 0;
            for (int j = 0; j < needTotal; ++j) r += (skeys[j] > s) ? 1 : 0;
            if (r < 10) selIdx[r] = t;
        }
        __syncthreads();

        if (t < 10) {
            unsigned long long key = lst[selIdx[t]];
            unsigned int fidx = ~(unsigned int)(key & 0xFFFFFFFFull);
            int aa = fidx % A; unsigned int rest = fidx / A;
            int gg = rest % G; rest /= G;
            int ww = rest % W; rest /= W;
            int hh = rest % H; int bb = rest / H;
            s_a[t] = aa; s_g[t] = gg; s_ww[t] = ww; s_hh[t] = hh; s_bb[t] = bb;
            s_pos[t] = (bb * H + hh) * W + ww;
        }
        __syncthreads();

        // flat cooperative gather for out[0..509]
        if (t < 510) {
            int e = t;
            float v;
            if (e < 50)       { int i = e / 5, f = e - 5 * i;
                                v = (float)((f==0)?s_bb[i]:(f==1)?s_hh[i]:(f==2)?s_ww[i]:(f==3)?s_g[i]:s_a[i]); }
            else if (e < 90)  { int u = e - 50, i = u >> 2, q = u & 3;
                                v = proposals[(size_t)(s_pos[i] * A + s_a[i]) * 4 + q]; }
            else if (e < 270) { int u = e - 90, i = u / 18, q = u - 18 * i;
                                v = cls_prob[(size_t)s_pos[i] * K + q]; }
            else if (e < 310) { int u = e - 270, i = u >> 2, q = u & 3;
                                v = gtp[s_g[i] * 4 + q]; }
            else if (e < 320) { v = (float)gtc[s_g[e - 310]]; }
            else if (e < 330) { v = (float)s_a[e - 320]; }
            else              { int u = e - 330, i = u / 18, q = u - 18 * i;
                                v = anchor_prob[(size_t)s_pos[i] * K + q]; }
            out[e] = v;
        }

        // reset device state for next replay — same block that read it
        __syncthreads();
        for (int i = t; i < NBIN; i += TPC) g_bincnt[i] = 0u;
        if (t == 0) g_spillCount = 0;

    } else {
        // ---------------- negatives: merge 6250 per-block top-10s (R12 verbatim) ----------------
        unsigned long long top[10];
#pragma unroll
        for (int j = 0; j < 10; ++j) top[j] = 0ull;
        for (int i = t; i < NB_P * 10; i += TPC) {
            unsigned long long key = g_negtop[i];
#pragma unroll
            for (int j = 0; j < 10; ++j) {
                if (key > top[j]) { unsigned long long tmp = top[j]; top[j] = key; key = tmp; }
            }
        }
        int lane = t & 63, wid = t >> 6;     // 8 waves
        for (int r = 0; r < 10; ++r) {
            unsigned long long w = top[0];
            for (int s = 1; s < 64; s <<= 1) {
                unsigned long long o = __shfl_xor(w, s);
                if (o > w) w = o;
            }
            if (lane == 0) wred[wid] = w;
            __syncthreads();
            unsigned long long m = wred[0];
#pragma unroll
            for (int i = 1; i < 8; ++i) { unsigned long long x = wred[i]; if (x > m) m = x; }
            if (t == 0) swin[r] = m;
            if (top[0] == m) {
#pragma unroll
                for (int j = 0; j < 9; ++j) top[j] = top[j + 1];
                top[9] = 0ull;
            }
            __syncthreads();
        }
        if (t < 10) s_npos[t] = (int)(~(unsigned int)(swin[t] & 0xFFFFFFFFull));
        __syncthreads();

        if (t < 210) {
            int e = 510 + t;
            float v;
            if (e < 540) { int u = e - 510, i = u / 3, f = u - 3 * i; int p = s_npos[i];
                           v = (float)((f==0) ? (p / (H * W)) : (f==1) ? ((p / W) % H) : (p % W)); }
            else         { int u = e - 540, i = u / 18, q = u - 18 * i;
                           v = cls_prob[(size_t)s_npos[i] * K + q]; }
            out[e] = v;
        }
    }
}

// ---------------- launcher ----------------
extern "C" void kernel_launch(void* const* d_in, const int* in_sizes, int n_in,
                              void* d_out, int out_size, void* d_ws, size_t ws_size,
                              hipStream_t stream) {
    const float* proposals   = (const float*)d_in[0];
    const float* cls_prob    = (const float*)d_in[1];
    const float* anchor_prob = (const float*)d_in[2];
    const float* gtp         = (const float*)d_in[3];
    const int*   gtc         = (const int*)d_in[4];
    float* out = (float*)d_out;

    prod_kernel<<<NB_P, TPB, 0, stream>>>(proposals, gtp);
    cons_kernel<<<2, TPC, 0, stream>>>(proposals, cls_prob, anchor_prob, gtp, gtc, out);
}

// Round 16
// 40.997 us; speedup vs baseline: 1.5933x; 1.0157x over previous
//
#include <hip/hip_runtime.h>

// ---------------- problem constants ----------------
constexpr int B = 8, H = 100, W = 100, A = 9, G = 50, K = 18;
constexpr int NPROP = B * H * W * A;   // 720000
constexpr int NPOS  = B * H * W;       // 80000
constexpr float THR = 0.7f;

#define JAX_PARTITIONABLE 1

#define TPB 576                  // 9 waves
#define NB_P 768                 // 3 blocks/CU exactly -> balanced
// position split: blocks 0..127 -> 105 positions, 128..767 -> 104  (128*105+640*104=80000)
#define TPC 512                  // consumer threads (8 waves) x 2 blocks
#define NBIN 2560                // bin = key>>43 = delta>>11; delta<=0x4CCCCC -> bin<=2457
#define BINCAP 512
#define SPILL_CAP 16384
#define BLK_CAND 1024

// ---------------- device state (zero at load; consumer resets each launch) ----
__device__ unsigned int g_bincnt[NBIN];
__device__ int g_spillCount;
__device__ unsigned long long g_bins[(size_t)NBIN * BINCAP];
__device__ unsigned long long g_spill[SPILL_CAP];
__device__ unsigned long long g_negtop[NB_P * 10];   // per-block neg top-10 (0-padded)

// ---------------- threefry2x32 (JAX-exact) ----------------
__device__ __forceinline__ unsigned int rotl32(unsigned int x, int r) {
    return (x << r) | (x >> (32 - r));
}
__device__ __forceinline__ void tfr(unsigned int& x0, unsigned int& x1, int r) {
    x0 += x1; x1 = rotl32(x1, r); x1 ^= x0;
}
__device__ void threefry2x32(unsigned int k0, unsigned int k1,
                             unsigned int c0, unsigned int c1,
                             unsigned int& o0, unsigned int& o1) {
    unsigned int ks2 = k0 ^ k1 ^ 0x1BD11BDAu;
    unsigned int x0 = c0 + k0, x1 = c1 + k1;
    tfr(x0,x1,13); tfr(x0,x1,15); tfr(x0,x1,26); tfr(x0,x1, 6);
    x0 += k1;  x1 += ks2 + 1u;
    tfr(x0,x1,17); tfr(x0,x1,29); tfr(x0,x1,16); tfr(x0,x1,24);
    x0 += ks2; x1 += k0 + 2u;
    tfr(x0,x1,13); tfr(x0,x1,15); tfr(x0,x1,26); tfr(x0,x1, 6);
    x0 += k0;  x1 += k1 + 3u;
    tfr(x0,x1,17); tfr(x0,x1,29); tfr(x0,x1,16); tfr(x0,x1,24);
    x0 += k1;  x1 += ks2 + 4u;
    tfr(x0,x1,13); tfr(x0,x1,15); tfr(x0,x1,26); tfr(x0,x1, 6);
    x0 += ks2; x1 += k0 + 5u;
    o0 = x0; o1 = x1;
}

__device__ void derive_keys(unsigned int& kp0, unsigned int& kp1,
                            unsigned int& kn0, unsigned int& kn1) {
#if JAX_PARTITIONABLE
    threefry2x32(0u, 42u, 0u, 0u, kp0, kp1);
    threefry2x32(0u, 42u, 0u, 1u, kn0, kn1);
#else
    unsigned int a0, b0, a1, b1;
    threefry2x32(0u, 42u, 0u, 2u, a0, b0);
    threefry2x32(0u, 42u, 1u, 3u, a1, b1);
    kp0 = a0; kp1 = a1; kn0 = b0; kn1 = b1;
#endif
}

__device__ float jax_uniform(unsigned int k0, unsigned int k1, unsigned int i, unsigned int n) {
    unsigned int bits;
#if JAX_PARTITIONABLE
    unsigned int o0, o1;
    threefry2x32(k0, k1, 0u, i, o0, o1);
    bits = o0 ^ o1;
#else
    unsigned int half = n >> 1;
    unsigned int o0, o1;
    if (i < half) { threefry2x32(k0, k1, i, i + half, o0, o1); bits = o0; }
    else          { threefry2x32(k0, k1, i - half, i, o0, o1); bits = o1; }
#endif
    unsigned int fb = (bits >> 9) | 0x3F800000u;
    return __uint_as_float(fb) - 1.0f;
}

__device__ __forceinline__ void emit_candidate(float iou, unsigned int idx) {
    unsigned int delta = __float_as_uint(iou) - 0x3F333334u;   // <= 0x4CCCCC
    unsigned long long key = ((unsigned long long)delta << 32)
                           | (unsigned long long)(~idx);
    unsigned int bin = (unsigned int)(key >> 43);              // <= 2457 < NBIN
    unsigned int slot = atomicAdd(&g_bincnt[bin], 1u);
    if (slot < BINCAP) g_bins[(size_t)bin * BINCAP + slot] = key;
    else { int gs = atomicAdd(&g_spillCount, 1);
           if (gs < SPILL_CAP) g_spill[gs] = key; }
}

// ======================= kernel 1: producers (balanced 768 blocks) =======================
__global__ __launch_bounds__(TPB) void prod_kernel(
        const float* __restrict__ proposals, const float* __restrict__ gtp) {
    __shared__ float  s41[G];           // 0.41 * area_g (only LDS read in hot loop)
    __shared__ unsigned int sflag[105];
    __shared__ unsigned long long snk[105];
    __shared__ unsigned long long wk[10];

    const int t = threadIdx.x;
    const int bid = blockIdx.x;
    const float4* gtp4 = reinterpret_cast<const float4*>(gtp);   // uniform -> scalar loads

    const int npos   = (bid < 128) ? 105 : 104;
    const int pstart = (bid < 128) ? bid * 105 : 13440 + (bid - 128) * 104;
    const int np     = npos * 9;        // proposals in this block (945 or 936)

    if (t < G) {
        float4 gb = gtp4[t];
        s41[t] = __fmul_rn(0.41f, __fmul_rn(__fsub_rn(gb.z, gb.x), __fsub_rn(gb.w, gb.y)));
    }
    if (t < npos) sflag[t] = 0u;
    __syncthreads();

    // box 0: j = t (always < np); box 1: j = t + TPB (if < np)
    const int j0 = t;
    const int j1 = t + TPB;
    const bool has1 = (j1 < np);
    const int gbase = pstart * 9;       // global proposal offset of this block

    float4 x0 = reinterpret_cast<const float4*>(proposals)[gbase + j0];
    float4 x1 = has1 ? reinterpret_cast<const float4*>(proposals)[gbase + j1]
                     : make_float4(0.f, 0.f, 0.f, 0.f);
    float ap0 = __fmul_rn(__fsub_rn(x0.z, x0.x), __fsub_rn(x0.w, x0.y));
    float ap1 = __fmul_rn(__fsub_rn(x1.z, x1.x), __fsub_rn(x1.w, x1.y));
    float a41_0 = __fmul_rn(0.41f, ap0);
    float a41_1 = has1 ? __fmul_rn(0.41f, ap1) : 1e30f;   // impossible threshold if absent
    int li0 = j0 / 9, a0 = j0 - li0 * 9;
    int li1 = j1 / 9, a1 = j1 - li1 * 9;
    int base0 = (pstart + li0) * (G * A) + a0;
    int base1 = (pstart + li1) * (G * A) + a1;
    unsigned f0 = 0u, f1 = 0u;

    for (int g = 0; g < G; ++g) {
        float4 gb = gtp4[g];            // wave-uniform -> scalar loads
        float sg41 = s41[g];
        {
            float dx = __fsub_rn(fminf(x0.z, gb.z), fmaxf(x0.x, gb.x));
            float dy = __fsub_rn(fminf(x0.w, gb.w), fmaxf(x0.y, gb.y));
            // one-clamp screen: pass => dy>0 => sc == clamped inter (bitwise)
            float sc = __fmul_rn(fmaxf(dx, 0.0f), dy);
            if (sc > __fadd_rn(a41_0, sg41)) {
                float ag = __fmul_rn(__fsub_rn(gb.z, gb.x), __fsub_rn(gb.w, gb.y));
                float den = __fadd_rn(__fsub_rn(__fadd_rn(ap0, ag), sc), 1e-8f);
                float iou = __fdiv_rn(sc, den);
                if (iou >= THR) f0 = 1u;
                if (iou > THR) emit_candidate(iou, (unsigned int)(base0 + g * A));
            }
        }
        {
            float dx = __fsub_rn(fminf(x1.z, gb.z), fmaxf(x1.x, gb.x));
            float dy = __fsub_rn(fminf(x1.w, gb.w), fmaxf(x1.y, gb.y));
            float sc = __fmul_rn(fmaxf(dx, 0.0f), dy);
            if (sc > __fadd_rn(a41_1, sg41)) {
                float ag = __fmul_rn(__fsub_rn(gb.z, gb.x), __fsub_rn(gb.w, gb.y));
                float den = __fadd_rn(__fsub_rn(__fadd_rn(ap1, ag), sc), 1e-8f);
                float iou = __fdiv_rn(sc, den);
                if (iou >= THR) f1 = 1u;
                if (iou > THR) emit_candidate(iou, (unsigned int)(base1 + g * A));
            }
        }
    }
    if (f0) atomicOr(&sflag[li0], 1u);
    if (f1) atomicOr(&sflag[li1], 1u);
    if (t < 10) wk[t] = 0ull;
    __syncthreads();

    // negative keys for this block's positions
    if (t < npos) {
        unsigned int kp0, kp1, kn0, kn1;
        derive_keys(kp0, kp1, kn0, kn1);
        unsigned long long key = 0ull;
        if (sflag[t] == 0u) {
            unsigned int pos = (unsigned)(pstart + t);
            float u = jax_uniform(kn0, kn1, pos, (unsigned)NPOS);
            key = ((unsigned long long)__float_as_uint(u) << 32)
                | (unsigned long long)(~pos);
        }
        snk[t] = key;
    }
    __syncthreads();
    if (t < npos) {
        unsigned long long k2 = snk[t];
        if (k2 != 0ull) {
            int r = 0;
            for (int j = 0; j < npos; ++j) r += (snk[j] > k2) ? 1 : 0;
            if (r < 10) wk[r] = k2;       // ranks unique (keys unique)
        }
    }
    __syncthreads();
    if (t < 10) g_negtop[bid * 10 + t] = wk[t];
}

// ============ kernel 2: consumer — block 0 positives, block 1 negatives ============
__global__ __launch_bounds__(TPC) void cons_kernel(
        const float* __restrict__ proposals, const float* __restrict__ cls_prob,
        const float* __restrict__ anchor_prob, const float* __restrict__ gtp,
        const int* __restrict__ gtc, float* __restrict__ out) {
    __shared__ unsigned int hist[NBIN];
    __shared__ int sfx[256];
    __shared__ unsigned int rhist[2048];
    __shared__ unsigned long long cbuf[BLK_CAND];
    __shared__ unsigned long long lst[100];
    __shared__ unsigned long long skeys[128];
    __shared__ unsigned long long swin[10];
    __shared__ unsigned long long wred[8];
    __shared__ int selIdx[10];
    __shared__ int s_g[10], s_a[10], s_pos[10], s_bb[10], s_hh[10], s_ww[10], s_npos[10];
    __shared__ int sh_d, sh_before, sh_C, sh_d2, sh_cnt, sh_ovf;

    const int t = threadIdx.x;

    if (blockIdx.x == 0) {
        // ---------------- positives (bucket-based, R14/R15-proven) ----------------
        for (int i = t; i < NBIN; i += TPC) hist[i] = g_bincnt[i];
        if (t == 0) { sh_d = NBIN - 1; sh_before = 0; sh_ovf = 0; sh_cnt = 0; }
        __syncthreads();
        if (t < 256) {
            int ps = 0;
            for (int q = 0; q < 10; ++q) ps += (int)hist[t * 10 + q];
            sfx[t] = ps;
        }
        __syncthreads();
        if (t < 64) {
            int lane = t;
            int c0 = sfx[4*lane+0], c1 = sfx[4*lane+1], c2 = sfx[4*lane+2], c3 = sfx[4*lane+3];
            int tot = c0 + c1 + c2 + c3;
            int acc = tot;
            for (int s = 1; s < 64; s <<= 1) {
                int u = __shfl_down(acc, s);
                if (lane + s < 64) acc += u;
            }
            int C = __shfl(acc, 0);           // total candidates
            if (lane == 0) sh_C = C;
            int need = C < 100 ? C : 100;
            int aboveG = acc - tot;
            int CS3 = aboveG;
            int CS2 = CS3 + c3;
            int CS1 = CS2 + c2;
            int CS0 = CS1 + c1;
            int CSv[4] = {CS0, CS1, CS2, CS3};
            int cv[4]  = {c0, c1, c2, c3};
#pragma unroll
            for (int j = 0; j < 4; ++j) {
                if (CSv[j] < need && CSv[j] + cv[j] >= need) {
                    int cum = CSv[j];
                    int cbin = 4*lane + j;
                    for (int b = cbin*10 + 9; b >= cbin*10; --b) {
                        int h = (int)hist[b];
                        if (cum + h >= need) { sh_d = b; sh_before = cum; break; }
                        cum += h;
                    }
                }
            }
        }
        __syncthreads();
        int C = sh_C;
        int needTotal = C < 100 ? C : 100;
        int d = sh_d, sb = sh_before;
        int tie = (int)hist[d];
        unsigned long long lo = ((unsigned long long)(unsigned)d) << 43;
        int spillN = g_spillCount; if (spillN > SPILL_CAP) spillN = SPILL_CAP;

        for (int b = d + t; b < NBIN; b += TPC)
            if (hist[b] > BINCAP) sh_ovf = 1;
        __syncthreads();

        if (sb + tie > BLK_CAND) {
            // cold refine: sub-histogram of bin d on remaining delta bits
            for (int i = t; i < 2048; i += TPC) rhist[i] = 0u;
            __syncthreads();
            int stored_d = tie < BINCAP ? tie : BINCAP;
            for (int i = t; i < stored_d; i += TPC) {
                unsigned long long k2 = g_bins[(size_t)d * BINCAP + i];
                atomicAdd(&rhist[(unsigned)(k2 >> 32) & 0x7FFu], 1u);
            }
            if (tie > BINCAP) {
                for (int i = t; i < spillN; i += TPC) {
                    unsigned long long k2 = g_spill[i];
                    if ((unsigned)(k2 >> 43) == (unsigned)d)
                        atomicAdd(&rhist[(unsigned)(k2 >> 32) & 0x7FFu], 1u);
                }
            }
            __syncthreads();
            if (t == 0) {
                int need = needTotal, cum = sb;
                sh_d2 = 0;
                for (int b2 = 2047; b2 >= 0; --b2) {
                    int h2 = (int)rhist[b2];
                    if (cum + h2 >= need) { sh_d2 = b2; break; }
                    cum += h2;
                }
            }
            __syncthreads();
            lo |= ((unsigned long long)(unsigned)sh_d2) << 32;
        }

        // gather keys >= lo from buckets d..NBIN (+ spill if any overflow)
        for (int b = d + t; b < NBIN; b += TPC) {
            int cnt_b = (int)hist[b]; if (cnt_b > BINCAP) cnt_b = BINCAP;
            for (int i = 0; i < cnt_b; ++i) {
                unsigned long long k2 = g_bins[(size_t)b * BINCAP + i];
                if (k2 >= lo) {
                    int s2 = atomicAdd(&sh_cnt, 1);
                    if (s2 < BLK_CAND) cbuf[s2] = k2;
                }
            }
        }
        if (sh_ovf) {
            for (int i = t; i < spillN; i += TPC) {
                unsigned long long k2 = g_spill[i];
                if (k2 >= lo) {
                    int s2 = atomicAdd(&sh_cnt, 1);
                    if (s2 < BLK_CAND) cbuf[s2] = k2;
                }
            }
        }
        __syncthreads();
        int M = sh_cnt < BLK_CAND ? sh_cnt : BLK_CAND;

        // sorted top-needTotal via parallel rank-count (keys unique)
        for (int i = t; i < M; i += TPC) {
            unsigned long long ki = cbuf[i];
            int r = 0;
            for (int j = 0; j < M; ++j) r += (cbuf[j] > ki) ? 1 : 0;
            if (r < needTotal) lst[r] = ki;
        }
        __syncthreads();

        unsigned int kp0, kp1, kn0, kn1;
        derive_keys(kp0, kp1, kn0, kn1);
        if (t < needTotal) {
            float u = jax_uniform(kp0, kp1, (unsigned)t, 100u);
            skeys[t] = ((unsigned long long)__float_as_uint(u) << 32)
                     | (unsigned long long)(~(unsigned)t);
        }
        __syncthreads();
        if (t < needTotal) {
            unsigned long long s = skeys[t];
            int r = 0;
            for (int j = 0; j < needTotal; ++j) r += (skeys[j] > s) ? 1 : 0;
            if (r < 10) selIdx[r] = t;
        }
        __syncthreads();

        if (t < 10) {
            unsigned long long key = lst[selIdx[t]];
            unsigned int fidx = ~(unsigned int)(key & 0xFFFFFFFFull);
            int aa = fidx % A; unsigned int rest = fidx / A;
            int gg = rest % G; rest /= G;
            int ww = rest % W; rest /= W;
            int hh = rest % H; int bb = rest / H;
            s_a[t] = aa; s_g[t] = gg; s_ww[t] = ww; s_hh[t] = hh; s_bb[t] = bb;
            s_pos[t] = (bb * H + hh) * W + ww;
        }
        __syncthreads();

        // flat cooperative gather for out[0..509]
        if (t < 510) {
            int e = t;
            float v;
            if (e < 50)       { int i = e / 5, f = e - 5 * i;
                                v = (float)((f==0)?s_bb[i]:(f==1)?s_hh[i]:(f==2)?s_ww[i]:(f==3)?s_g[i]:s_a[i]); }
            else if (e < 90)  { int u = e - 50, i = u >> 2, q = u & 3;
                                v = proposals[(size_t)(s_pos[i] * A + s_a[i]) * 4 + q]; }
            else if (e < 270) { int u = e - 90, i = u / 18, q = u - 18 * i;
                                v = cls_prob[(size_t)s_pos[i] * K + q]; }
            else if (e < 310) { int u = e - 270, i = u >> 2, q = u & 3;
                                v = gtp[s_g[i] * 4 + q]; }
            else if (e < 320) { v = (float)gtc[s_g[e - 310]]; }
            else if (e < 330) { v = (float)s_a[e - 320]; }
            else              { int u = e - 330, i = u / 18, q = u - 18 * i;
                                v = anchor_prob[(size_t)s_pos[i] * K + q]; }
            out[e] = v;
        }

        // reset device state for next replay — same block that read it
        __syncthreads();
        for (int i = t; i < NBIN; i += TPC) g_bincnt[i] = 0u;
        if (t == 0) g_spillCount = 0;

    } else {
        // ---------------- negatives: merge 7680 per-block top-10s ----------------
        unsigned long long top[10];
#pragma unroll
        for (int j = 0; j < 10; ++j) top[j] = 0ull;
        for (int i = t; i < NB_P * 10; i += TPC) {
            unsigned long long key = g_negtop[i];
#pragma unroll
            for (int j = 0; j < 10; ++j) {
                if (key > top[j]) { unsigned long long tmp = top[j]; top[j] = key; key = tmp; }
            }
        }
        int lane = t & 63, wid = t >> 6;     // 8 waves
        for (int r = 0; r < 10; ++r) {
            unsigned long long w = top[0];
            for (int s = 1; s < 64; s <<= 1) {
                unsigned long long o = __shfl_xor(w, s);
                if (o > w) w = o;
            }
            if (lane == 0) wred[wid] = w;
            __syncthreads();
            unsigned long long m = wred[0];
#pragma unroll
            for (int i = 1; i < 8; ++i) { unsigned long long x = wred[i]; if (x > m) m = x; }
            if (t == 0) swin[r] = m;
            if (top[0] == m) {
#pragma unroll
                for (int j = 0; j < 9; ++j) top[j] = top[j + 1];
                top[9] = 0ull;
            }
            __syncthreads();
        }
        if (t < 10) s_npos[t] = (int)(~(unsigned int)(swin[t] & 0xFFFFFFFFull));
        __syncthreads();

        if (t < 210) {
            int e = 510 + t;
            float v;
            if (e < 540) { int u = e - 510, i = u / 3, f = u - 3 * i; int p = s_npos[i];
                           v = (float)((f==0) ? (p / (H * W)) : (f==1) ? ((p / W) % H) : (p % W)); }
            else         { int u = e - 540, i = u / 18, q = u - 18 * i;
                           v = cls_prob[(size_t)s_npos[i] * K + q]; }
            out[e] = v;
        }
    }
}

// ---------------- launcher ----------------
extern "C" void kernel_launch(void* const* d_in, const int* in_sizes, int n_in,
                              void* d_out, int out_size, void* d_ws, size_t ws_size,
                              hipStream_t stream) {
    const float* proposals   = (const float*)d_in[0];
    const float* cls_prob    = (const float*)d_in[1];
    const float* anchor_prob = (const float*)d_in[2];
    const float* gtp         = (const float*)d_in[3];
    const int*   gtc         = (const int*)d_in[4];
    float* out = (float*)d_out;

    prod_kernel<<<NB_P, TPB, 0, stream>>>(proposals, gtp);
    cons_kernel<<<2, TPC, 0, stream>>>(proposals, cls_prob, anchor_prob, gtp, gtc, out);
}